// Round 3
// baseline (395.696 us; speedup 1.0000x reference)
//
#include <hip/hip_runtime.h>
#include <hip/hip_bf16.h>

#define DM 1024
#define NH 16
#define HD 64
#define BATCH 2
#define SEQ 2048
#define MROWS (BATCH*SEQ)   // 4096

typedef __attribute__((ext_vector_type(8))) short bf16x8;
typedef __attribute__((ext_vector_type(4))) short bf16x4;
typedef __attribute__((ext_vector_type(4))) float f32x4;

__device__ __forceinline__ short f2b(float f) {
  union { float f; unsigned u; } x; x.f = f;
  unsigned r = x.u + 0x7fffu + ((x.u >> 16) & 1u);
  return (short)(r >> 16);
}

__device__ __forceinline__ void gload16(const void* g, void* l) {
  __builtin_amdgcn_global_load_lds((const __attribute__((address_space(1))) unsigned int*)g,
                                   (__attribute__((address_space(3))) unsigned int*)l, 16, 0, 0);
}

// ---------------- prep kernels ----------------

__global__ void k_conv(const float* __restrict__ src, short* __restrict__ dst, int n) {
  int i = (blockIdx.x * 256 + threadIdx.x) * 8;
  if (i >= n) return;
  const float4* s4 = (const float4*)(src + i);
  float4 a = s4[0], b = s4[1];
  bf16x8 o;
  o[0]=f2b(a.x); o[1]=f2b(a.y); o[2]=f2b(a.z); o[3]=f2b(a.w);
  o[4]=f2b(b.x); o[5]=f2b(b.y); o[6]=f2b(b.z); o[7]=f2b(b.w);
  *(bf16x8*)(dst + i) = o;
}

// Wq rows scaled by sigmoid(gate[row]) * 0.125 (fold in 1/sqrt(HD))
__global__ void k_conv_gate(const float* __restrict__ Wq, const float* __restrict__ gate,
                            short* __restrict__ dst) {
  int i = (blockIdx.x * 256 + threadIdx.x) * 8;
  int row = i >> 10;
  float sg = 0.125f / (1.f + __expf(-gate[row]));
  const float4* s4 = (const float4*)(Wq + i);
  float4 a = s4[0], b = s4[1];
  bf16x8 o;
  o[0]=f2b(a.x*sg); o[1]=f2b(a.y*sg); o[2]=f2b(a.z*sg); o[3]=f2b(a.w*sg);
  o[4]=f2b(b.x*sg); o[5]=f2b(b.y*sg); o[6]=f2b(b.z*sg); o[7]=f2b(b.w*sg);
  *(bf16x8*)(dst + i) = o;
}

// Wk_ent[h*64+e][c] = sum_d ent[h][d][e] * Wk[h*64+d][c]
__global__ void k_went(const float* __restrict__ Wk, const float* __restrict__ ent,
                       short* __restrict__ dst) {
  int r = blockIdx.x;            // 0..1023
  int h = r >> 6, e = r & 63;
  int c = blockIdx.y * 256 + threadIdx.x;
  float acc = 0.f;
#pragma unroll 8
  for (int d = 0; d < 64; ++d)
    acc += ent[h*4096 + d*64 + e] * Wk[(size_t)(h*64 + d)*DM + c];
  dst[(size_t)r*DM + c] = f2b(acc);
}

__global__ void k_bias(const float* __restrict__ bq, const float* __restrict__ bk,
                       const float* __restrict__ bv, const float* __restrict__ gate,
                       const float* __restrict__ ent, float* __restrict__ bcat) {
  int i = blockIdx.x * 256 + threadIdx.x;  // < 3072
  float v;
  if (i < 1024) {
    v = bq[i] * (0.125f / (1.f + __expf(-gate[i])));
  } else if (i < 2048) {
    int rr = i - 1024, h = rr >> 6, e = rr & 63;
    float a = 0.f;
    for (int d = 0; d < 64; ++d) a += bk[h*64 + d] * ent[h*4096 + d*64 + e];
    v = a;
  } else {
    v = bv[i - 2048];
  }
  bcat[i] = v;
}

// ---------------- GEMM: C[m,n] = sum_k A[m,k]*B[n,k] + bias[n] ----------------
// MODE 0: fp32 C row-major (stride N). MODE 1: cols<2048 -> bf16 QK buffer
// (stride 2048); cols>=2048 -> V written TRANSPOSED into vt[bh][d][s].

template<int MODE>
__global__ __launch_bounds__(256) void gemm_bt(const short* __restrict__ A,
                                               const short* __restrict__ B,
                                               const float* __restrict__ bias,
                                               void* __restrict__ C,
                                               short* __restrict__ vt,
                                               int M, int N, int K) {
  __shared__ __align__(16) short As[128*64];
  __shared__ __align__(16) short Bs[128*64];
  const int t = threadIdx.x, l = t & 63, w = t >> 6;
  const int wr = w >> 1, wc = w & 1;
  const int bm = blockIdx.x, bn = blockIdx.y;
  const int row_l = l & 15, kg = l >> 4;
  f32x4 acc[4][4];
  {
    f32x4 z = {0.f, 0.f, 0.f, 0.f};
#pragma unroll
    for (int m = 0; m < 4; ++m)
#pragma unroll
      for (int n = 0; n < 4; ++n) acc[m][n] = z;
  }
  for (int k0 = 0; k0 < K; k0 += 64) {
#pragma unroll
    for (int i = 0; i < 4; ++i) {
      int idx = i * 256 + t;
      int row = idx >> 3, cb = (idx & 7) * 8;
      gload16(A + (size_t)(bm*128 + row)*K + k0 + cb, &As[idx*8]);
      gload16(B + (size_t)(bn*128 + row)*K + k0 + cb, &Bs[idx*8]);
    }
    __syncthreads();
#pragma unroll
    for (int ks = 0; ks < 2; ++ks) {
      bf16x8 af[4], bfv[4];
#pragma unroll
      for (int m = 0; m < 4; ++m)
        af[m] = *(const bf16x8*)&As[(wr*64 + m*16 + row_l)*64 + ks*32 + kg*8];
#pragma unroll
      for (int n = 0; n < 4; ++n)
        bfv[n] = *(const bf16x8*)&Bs[(wc*64 + n*16 + row_l)*64 + ks*32 + kg*8];
#pragma unroll
      for (int m = 0; m < 4; ++m)
#pragma unroll
        for (int n = 0; n < 4; ++n)
          acc[m][n] = __builtin_amdgcn_mfma_f32_16x16x32_bf16(af[m], bfv[n], acc[m][n], 0, 0, 0);
    }
    __syncthreads();
  }
  const int r0 = bm*128 + wr*64, c0 = bn*128 + wc*64;
  if (MODE == 1 && c0 >= 2048) {
    // V region: write transposed vt[(b*16+h)*64 + d][s]
    const int bb = (bm*128) >> 11;
#pragma unroll
    for (int n = 0; n < 4; ++n) {
      int cv = c0 + n*16 + row_l - 2048;
      int hh = cv >> 6, dd = cv & 63;
      float bvs = bias[c0 + n*16 + row_l];
      short* vrow = vt + ((size_t)((bb*16 + hh)*64 + dd))*SEQ;
#pragma unroll
      for (int m = 0; m < 4; ++m) {
        int s0 = (r0 + m*16 + kg*4) & (SEQ-1);
        bf16x4 o;
        o[0]=f2b(acc[m][n][0]+bvs); o[1]=f2b(acc[m][n][1]+bvs);
        o[2]=f2b(acc[m][n][2]+bvs); o[3]=f2b(acc[m][n][3]+bvs);
        *(bf16x4*)&vrow[s0] = o;
      }
    }
  } else {
#pragma unroll
    for (int n = 0; n < 4; ++n) {
      int col = c0 + n*16 + row_l;
      float bvs = bias[col];
#pragma unroll
      for (int m = 0; m < 4; ++m) {
#pragma unroll
        for (int r = 0; r < 4; ++r) {
          int row = r0 + m*16 + kg*4 + r;
          float v = acc[m][n][r] + bvs;
          if (MODE == 1) ((short*)C)[(size_t)row*2048 + col] = f2b(v);
          else           ((float*)C)[(size_t)row*N + col] = v;
        }
      }
    }
  }
}

// ---------------- fused attention ----------------
// qk: (4096 x 2048) bf16: Q at col h*64, K' at 1024+h*64 (Q pre-scaled by 1/8).
// vtg: [bh][d][s] bf16. Pass 1: barrier-free, K direct from global.
// Pass 2: K direct; V double-buffered in LDS (1 barrier/tile); attn nontemporal.

__global__ __launch_bounds__(256, 4) void attn_fused(const short* __restrict__ qk,
                                                     const short* __restrict__ vtg,
                                                     float* __restrict__ attn_out,
                                                     short* __restrict__ ctx) {
  __shared__ __align__(16) short Vt[2][64*72];   // [d][key] stride 72
  __shared__ __align__(16) short Ps[4][16*72];   // per-wave P[q][key]
  const int t = threadIdx.x, l = t & 63, w = t >> 6;
  const int row_l = l & 15, kg = l >> 4;
  const int blk = blockIdx.x;
  const int bh = blk >> 5, q0 = (blk & 31) * 64;
  const int b = bh >> 4, h = bh & 15;
  const short* Qp = qk + (size_t)b*SEQ*2048 + h*64;
  const short* Kp = qk + (size_t)b*SEQ*2048 + 1024 + h*64;
  const short* Vg = vtg + (size_t)bh*64*SEQ;
  float* attn_bh = attn_out + (size_t)bh*SEQ*SEQ;
  const int qw = q0 + w*16;

  const bf16x8 aq0 = *(const bf16x8*)(Qp + (size_t)(qw + row_l)*2048 + kg*8);
  const bf16x8 aq1 = *(const bf16x8*)(Qp + (size_t)(qw + row_l)*2048 + 32 + kg*8);

  // ---- pass 1: rsum, no LDS, no barriers ----
  float rsum = 0.f;
#pragma unroll 2
  for (int kt = 0; kt < 32; ++kt) {
    const short* kb = Kp + (size_t)kt*64*2048;
#pragma unroll
    for (int nt = 0; nt < 4; ++nt) {
      bf16x8 k0 = *(const bf16x8*)(kb + (size_t)(nt*16 + row_l)*2048 + kg*8);
      bf16x8 k1 = *(const bf16x8*)(kb + (size_t)(nt*16 + row_l)*2048 + 32 + kg*8);
      f32x4 s = {0.f, 0.f, 0.f, 0.f};
      s = __builtin_amdgcn_mfma_f32_16x16x32_bf16(k0, aq0, s, 0, 0, 0);
      s = __builtin_amdgcn_mfma_f32_16x16x32_bf16(k1, aq1, s, 0, 0, 0);
      rsum += __expf(s[0]) + __expf(s[1]) + __expf(s[2]) + __expf(s[3]);
    }
  }
  rsum += __shfl_xor(rsum, 16);
  rsum += __shfl_xor(rsum, 32);
  const float inv = 1.f / rsum;

  f32x4 actx[4];
  {
    f32x4 z = {0.f, 0.f, 0.f, 0.f};
#pragma unroll
    for (int e = 0; e < 4; ++e) actx[e] = z;
  }

  // V staging slots (2 per thread)
  const int vrow0 = t >> 3, vcb = (t & 7) * 8;
  const int vrow1 = vrow0 + 32;

  // prologue: stage V tile 0 into buf 0
  {
    bf16x8 v0 = *(const bf16x8*)(Vg + (size_t)vrow0*SEQ + vcb);
    bf16x8 v1 = *(const bf16x8*)(Vg + (size_t)vrow1*SEQ + vcb);
    *(bf16x8*)&Vt[0][vrow0*72 + vcb] = v0;
    *(bf16x8*)&Vt[0][vrow1*72 + vcb] = v1;
  }
  __syncthreads();

  // ---- pass 2: recompute, write attn (nontemporal), PV ----
#pragma unroll 1
  for (int kt = 0; kt < 32; ++kt) {
    const int cur = kt & 1;
    bf16x8 nv0, nv1;
    if (kt < 31) {
      const short* vb = Vg + (kt + 1)*64;
      nv0 = *(const bf16x8*)(vb + (size_t)vrow0*SEQ + vcb);
      nv1 = *(const bf16x8*)(vb + (size_t)vrow1*SEQ + vcb);
    }
    const short* kb = Kp + (size_t)kt*64*2048;
#pragma unroll
    for (int nt = 0; nt < 4; ++nt) {
      bf16x8 k0 = *(const bf16x8*)(kb + (size_t)(nt*16 + row_l)*2048 + kg*8);
      bf16x8 k1 = *(const bf16x8*)(kb + (size_t)(nt*16 + row_l)*2048 + 32 + kg*8);
      f32x4 s = {0.f, 0.f, 0.f, 0.f};
      s = __builtin_amdgcn_mfma_f32_16x16x32_bf16(k0, aq0, s, 0, 0, 0);
      s = __builtin_amdgcn_mfma_f32_16x16x32_bf16(k1, aq1, s, 0, 0, 0);
      f32x4 p;
      p[0] = __expf(s[0]) * inv; p[1] = __expf(s[1]) * inv;
      p[2] = __expf(s[2]) * inv; p[3] = __expf(s[3]) * inv;
      __builtin_nontemporal_store(p, (f32x4*)&attn_bh[(size_t)(qw + row_l)*SEQ + kt*64 + nt*16 + kg*4]);
      bf16x4 pb4;
      pb4[0] = f2b(p[0]); pb4[1] = f2b(p[1]); pb4[2] = f2b(p[2]); pb4[3] = f2b(p[3]);
      *(bf16x4*)&Ps[w][row_l*72 + nt*16 + kg*4] = pb4;
    }
    // in-wave relay: all lanes' Ps writes must land before Ps reads
    asm volatile("s_waitcnt lgkmcnt(0)" ::: "memory");
    __builtin_amdgcn_sched_barrier(0);
#pragma unroll
    for (int half = 0; half < 2; ++half) {
      bf16x8 pb = *(const bf16x8*)&Ps[w][row_l*72 + half*32 + kg*8];
#pragma unroll
      for (int e = 0; e < 4; ++e) {
        bf16x8 va = *(const bf16x8*)&Vt[cur][(e*16 + row_l)*72 + half*32 + kg*8];
        actx[e] = __builtin_amdgcn_mfma_f32_16x16x32_bf16(va, pb, actx[e], 0, 0, 0);
      }
    }
    if (kt < 31) {
      *(bf16x8*)&Vt[cur^1][vrow0*72 + vcb] = nv0;
      *(bf16x8*)&Vt[cur^1][vrow1*72 + vcb] = nv1;
    }
    __syncthreads();
  }
  // ctx epilogue: actx[e] = ctx^T: row d = e*16+kg*4+r, col q = row_l
#pragma unroll
  for (int e = 0; e < 4; ++e) {
    bf16x4 o;
    o[0] = f2b(actx[e][0]); o[1] = f2b(actx[e][1]);
    o[2] = f2b(actx[e][2]); o[3] = f2b(actx[e][3]);
    *(bf16x4*)&ctx[(size_t)(b*SEQ + qw + row_l)*DM + h*64 + e*16 + kg*4] = o;
  }
}

// ---------------- launch ----------------

extern "C" void kernel_launch(void* const* d_in, const int* in_sizes, int n_in,
                              void* d_out, int out_size, void* d_ws, size_t ws_size,
                              hipStream_t stream) {
  const float* x    = (const float*)d_in[0];
  const float* Wq   = (const float*)d_in[1];
  const float* bq   = (const float*)d_in[2];
  const float* Wk   = (const float*)d_in[3];
  const float* bk   = (const float*)d_in[4];
  const float* Wv   = (const float*)d_in[5];
  const float* bv   = (const float*)d_in[6];
  const float* Wo   = (const float*)d_in[7];
  const float* bo   = (const float*)d_in[8];
  const float* gate = (const float*)d_in[9];
  const float* ent  = (const float*)d_in[10];

  char* ws = (char*)d_ws;
  short* xb   = (short*)(ws);                          // 4096x1024 bf16 (8 MB); reused as ctx
  short* Wcat = (short*)(ws + ((size_t)8  << 20));     // 3072x1024 bf16 (6 MB)
  short* Wob  = (short*)(ws + ((size_t)14 << 20));     // 1024x1024 bf16 (2 MB)
  float* bcat = (float*)(ws + ((size_t)16 << 20));     // 3072 f32
  short* qkb  = (short*)(ws + ((size_t)17 << 20));     // 4096x2048 bf16 (16 MB)
  short* vtg  = (short*)(ws + ((size_t)33 << 20));     // 32x64x2048 bf16 (16 MB)
  short* ctxb = xb;                                    // reuse (x consumed by gemm1)

  float* outp  = (float*)d_out;
  float* attnp = outp + (size_t)MROWS * DM;

  k_conv<<<2048, 256, 0, stream>>>(x, xb, MROWS*DM);
  k_conv_gate<<<512, 256, 0, stream>>>(Wq, gate, Wcat);
  k_went<<<dim3(1024, 4), 256, 0, stream>>>(Wk, ent, Wcat + (size_t)1024*DM);
  k_conv<<<512, 256, 0, stream>>>(Wv, Wcat + (size_t)2048*DM, 1024*1024);
  k_conv<<<512, 256, 0, stream>>>(Wo, Wob, 1024*1024);
  k_bias<<<12, 256, 0, stream>>>(bq, bk, bv, gate, ent, bcat);

  gemm_bt<1><<<dim3(32, 24), 256, 0, stream>>>(xb, Wcat, bcat, qkb, vtg, MROWS, 3072, DM);
  attn_fused<<<1024, 256, 0, stream>>>(qkb, vtg, attnp, ctxb);
  gemm_bt<0><<<dim3(32, 8), 256, 0, stream>>>(ctxb, Wob, bo, outp, nullptr, MROWS, DM, DM);
}

// Round 4
// 335.100 us; speedup vs baseline: 1.1808x; 1.1808x over previous
//
#include <hip/hip_runtime.h>
#include <hip/hip_bf16.h>

#define DM 1024
#define NH 16
#define HD 64
#define BATCH 2
#define SEQ 2048
#define MROWS (BATCH*SEQ)   // 4096

typedef __attribute__((ext_vector_type(8))) short bf16x8;
typedef __attribute__((ext_vector_type(4))) short bf16x4;
typedef __attribute__((ext_vector_type(4))) float f32x4;

__device__ __forceinline__ short f2b(float f) {
  union { float f; unsigned u; } x; x.f = f;
  unsigned r = x.u + 0x7fffu + ((x.u >> 16) & 1u);
  return (short)(r >> 16);
}

__device__ __forceinline__ void gload16(const void* g, void* l) {
  __builtin_amdgcn_global_load_lds((const __attribute__((address_space(1))) unsigned int*)g,
                                   (__attribute__((address_space(3))) unsigned int*)l, 16, 0, 0);
}

// ---------------- prep kernels ----------------

__global__ void k_conv(const float* __restrict__ src, short* __restrict__ dst, int n) {
  int i = (blockIdx.x * 256 + threadIdx.x) * 8;
  if (i >= n) return;
  const float4* s4 = (const float4*)(src + i);
  float4 a = s4[0], b = s4[1];
  bf16x8 o;
  o[0]=f2b(a.x); o[1]=f2b(a.y); o[2]=f2b(a.z); o[3]=f2b(a.w);
  o[4]=f2b(b.x); o[5]=f2b(b.y); o[6]=f2b(b.z); o[7]=f2b(b.w);
  *(bf16x8*)(dst + i) = o;
}

// Wq rows scaled by sigmoid(gate[row]) * 0.125 (fold in 1/sqrt(HD))
__global__ void k_conv_gate(const float* __restrict__ Wq, const float* __restrict__ gate,
                            short* __restrict__ dst) {
  int i = (blockIdx.x * 256 + threadIdx.x) * 8;
  int row = i >> 10;
  float sg = 0.125f / (1.f + __expf(-gate[row]));
  const float4* s4 = (const float4*)(Wq + i);
  float4 a = s4[0], b = s4[1];
  bf16x8 o;
  o[0]=f2b(a.x*sg); o[1]=f2b(a.y*sg); o[2]=f2b(a.z*sg); o[3]=f2b(a.w*sg);
  o[4]=f2b(b.x*sg); o[5]=f2b(b.y*sg); o[6]=f2b(b.z*sg); o[7]=f2b(b.w*sg);
  *(bf16x8*)(dst + i) = o;
}

// Wk_ent[h*64+e][c] = sum_d ent[h][d][e] * Wk[h*64+d][c]
__global__ void k_went(const float* __restrict__ Wk, const float* __restrict__ ent,
                       short* __restrict__ dst) {
  int r = blockIdx.x;            // 0..1023
  int h = r >> 6, e = r & 63;
  int c = blockIdx.y * 256 + threadIdx.x;
  float acc = 0.f;
#pragma unroll 8
  for (int d = 0; d < 64; ++d)
    acc += ent[h*4096 + d*64 + e] * Wk[(size_t)(h*64 + d)*DM + c];
  dst[(size_t)r*DM + c] = f2b(acc);
}

__global__ void k_bias(const float* __restrict__ bq, const float* __restrict__ bk,
                       const float* __restrict__ bv, const float* __restrict__ gate,
                       const float* __restrict__ ent, float* __restrict__ bcat) {
  int i = blockIdx.x * 256 + threadIdx.x;  // < 3072
  float v;
  if (i < 1024) {
    v = bq[i] * (0.125f / (1.f + __expf(-gate[i])));
  } else if (i < 2048) {
    int rr = i - 1024, h = rr >> 6, e = rr & 63;
    float a = 0.f;
    for (int d = 0; d < 64; ++d) a += bk[h*64 + d] * ent[h*4096 + d*64 + e];
    v = a;
  } else {
    v = bv[i - 2048];
  }
  bcat[i] = v;
}

// ---------------- GEMM: C[m,n] = sum_k A[m,k]*B[n,k] + bias[n] ----------------
// MODE 0: fp32 C row-major (stride N). MODE 1: cols<2048 -> bf16 QK buffer
// (stride 2048); cols>=2048 -> V written TRANSPOSED into vt[bh][d][s].

template<int MODE>
__global__ __launch_bounds__(256) void gemm_bt(const short* __restrict__ A,
                                               const short* __restrict__ B,
                                               const float* __restrict__ bias,
                                               void* __restrict__ C,
                                               short* __restrict__ vt,
                                               int M, int N, int K) {
  __shared__ __align__(16) short As[128*64];
  __shared__ __align__(16) short Bs[128*64];
  const int t = threadIdx.x, l = t & 63, w = t >> 6;
  const int wr = w >> 1, wc = w & 1;
  const int bm = blockIdx.x, bn = blockIdx.y;
  const int row_l = l & 15, kg = l >> 4;
  f32x4 acc[4][4];
  {
    f32x4 z = {0.f, 0.f, 0.f, 0.f};
#pragma unroll
    for (int m = 0; m < 4; ++m)
#pragma unroll
      for (int n = 0; n < 4; ++n) acc[m][n] = z;
  }
  for (int k0 = 0; k0 < K; k0 += 64) {
#pragma unroll
    for (int i = 0; i < 4; ++i) {
      int idx = i * 256 + t;
      int row = idx >> 3, cb = (idx & 7) * 8;
      gload16(A + (size_t)(bm*128 + row)*K + k0 + cb, &As[idx*8]);
      gload16(B + (size_t)(bn*128 + row)*K + k0 + cb, &Bs[idx*8]);
    }
    __syncthreads();
#pragma unroll
    for (int ks = 0; ks < 2; ++ks) {
      bf16x8 af[4], bfv[4];
#pragma unroll
      for (int m = 0; m < 4; ++m)
        af[m] = *(const bf16x8*)&As[(wr*64 + m*16 + row_l)*64 + ks*32 + kg*8];
#pragma unroll
      for (int n = 0; n < 4; ++n)
        bfv[n] = *(const bf16x8*)&Bs[(wc*64 + n*16 + row_l)*64 + ks*32 + kg*8];
#pragma unroll
      for (int m = 0; m < 4; ++m)
#pragma unroll
        for (int n = 0; n < 4; ++n)
          acc[m][n] = __builtin_amdgcn_mfma_f32_16x16x32_bf16(af[m], bfv[n], acc[m][n], 0, 0, 0);
    }
    __syncthreads();
  }
  const int r0 = bm*128 + wr*64, c0 = bn*128 + wc*64;
  if (MODE == 1 && c0 >= 2048) {
    // V region: write transposed vt[(b*16+h)*64 + d][s]
    const int bb = (bm*128) >> 11;
#pragma unroll
    for (int n = 0; n < 4; ++n) {
      int cv = c0 + n*16 + row_l - 2048;
      int hh = cv >> 6, dd = cv & 63;
      float bvs = bias[c0 + n*16 + row_l];
      short* vrow = vt + ((size_t)((bb*16 + hh)*64 + dd))*SEQ;
#pragma unroll
      for (int m = 0; m < 4; ++m) {
        int s0 = (r0 + m*16 + kg*4) & (SEQ-1);
        bf16x4 o;
        o[0]=f2b(acc[m][n][0]+bvs); o[1]=f2b(acc[m][n][1]+bvs);
        o[2]=f2b(acc[m][n][2]+bvs); o[3]=f2b(acc[m][n][3]+bvs);
        *(bf16x4*)&vrow[s0] = o;
      }
    }
  } else {
#pragma unroll
    for (int n = 0; n < 4; ++n) {
      int col = c0 + n*16 + row_l;
      float bvs = bias[col];
#pragma unroll
      for (int m = 0; m < 4; ++m) {
#pragma unroll
        for (int r = 0; r < 4; ++r) {
          int row = r0 + m*16 + kg*4 + r;
          float v = acc[m][n][r] + bvs;
          if (MODE == 1) ((short*)C)[(size_t)row*2048 + col] = f2b(v);
          else           ((float*)C)[(size_t)row*N + col] = v;
        }
      }
    }
  }
}

// ---------------- fused attention ----------------
// qk: (4096 x 2048) bf16: Q at col h*64, K' at 1024+h*64 (Q pre-scaled by 1/8).
// vtg: [bh][d][s] bf16 (pre-transposed V). Both passes: K (and V) double-buffered
// in LDS, issue-early/write-late staging, ONE barrier per tile.

__global__ __launch_bounds__(256) void attn_fused(const short* __restrict__ qk,
                                                  const short* __restrict__ vtg,
                                                  float* __restrict__ attn_out,
                                                  short* __restrict__ ctx) {
  __shared__ __align__(16) short Ks[2][64*72];   // [key][d] stride 72
  __shared__ __align__(16) short Vt[2][64*72];   // [d][key] stride 72
  __shared__ __align__(16) short Ps[4][16*72];   // per-wave P[q][key]
  const int t = threadIdx.x, l = t & 63, w = t >> 6;
  const int row_l = l & 15, kg = l >> 4;
  const int blk = blockIdx.x;
  const int bh = blk >> 5, q0 = (blk & 31) * 64;
  const int b = bh >> 4, h = bh & 15;
  const short* Qp = qk + (size_t)b*SEQ*2048 + h*64;
  const short* Kp = qk + (size_t)b*SEQ*2048 + 1024 + h*64;
  const short* Vg = vtg + (size_t)bh*64*SEQ;
  float* attn_bh = attn_out + (size_t)bh*SEQ*SEQ;
  const int qw = q0 + w*16;

  const bf16x8 aq0 = *(const bf16x8*)(Qp + (size_t)(qw + row_l)*2048 + kg*8);
  const bf16x8 aq1 = *(const bf16x8*)(Qp + (size_t)(qw + row_l)*2048 + 32 + kg*8);

  // staging slots: K tile via (kr, cb); V tile via (vrow, vcb)
  const int kr0 = t >> 3, cb0 = (t & 7) * 8;        // rows 0..31
  const int kr1 = kr0 + 32;                          // rows 32..63
  const int vrow0 = t >> 3, vcb = (t & 7) * 8;
  const int vrow1 = vrow0 + 32;

  // ---- pass 1: rsum with double-buffered K, 1 barrier/tile ----
  float rsum = 0.f;
  {
    bf16x8 rk0 = *(const bf16x8*)(Kp + (size_t)kr0*2048 + cb0);
    bf16x8 rk1 = *(const bf16x8*)(Kp + (size_t)kr1*2048 + cb0);
    *(bf16x8*)&Ks[0][kr0*72 + cb0] = rk0;
    *(bf16x8*)&Ks[0][kr1*72 + cb0] = rk1;
  }
  __syncthreads();
#pragma unroll 1
  for (int kt = 0; kt < 32; ++kt) {
    const int cur = kt & 1;
    bf16x8 rk0, rk1;
    if (kt < 31) {
      const short* kb = Kp + (size_t)(kt + 1)*64*2048;
      rk0 = *(const bf16x8*)(kb + (size_t)kr0*2048 + cb0);
      rk1 = *(const bf16x8*)(kb + (size_t)kr1*2048 + cb0);
    }
#pragma unroll
    for (int nt = 0; nt < 4; ++nt) {
      bf16x8 k0 = *(const bf16x8*)&Ks[cur][(nt*16 + row_l)*72 + kg*8];
      bf16x8 k1 = *(const bf16x8*)&Ks[cur][(nt*16 + row_l)*72 + 32 + kg*8];
      f32x4 s = {0.f, 0.f, 0.f, 0.f};
      s = __builtin_amdgcn_mfma_f32_16x16x32_bf16(k0, aq0, s, 0, 0, 0);
      s = __builtin_amdgcn_mfma_f32_16x16x32_bf16(k1, aq1, s, 0, 0, 0);
      rsum += __expf(s[0]) + __expf(s[1]) + __expf(s[2]) + __expf(s[3]);
    }
    if (kt < 31) {
      *(bf16x8*)&Ks[cur^1][kr0*72 + cb0] = rk0;
      *(bf16x8*)&Ks[cur^1][kr1*72 + cb0] = rk1;
    }
    __syncthreads();
  }
  rsum += __shfl_xor(rsum, 16);
  rsum += __shfl_xor(rsum, 32);
  const float inv = 1.f / rsum;

  f32x4 actx[4];
  {
    f32x4 z = {0.f, 0.f, 0.f, 0.f};
#pragma unroll
    for (int e = 0; e < 4; ++e) actx[e] = z;
  }

  // ---- pass 2: recompute, write attn, PV; K+V double-buffered, 1 barrier ----
  {
    bf16x8 rk0 = *(const bf16x8*)(Kp + (size_t)kr0*2048 + cb0);
    bf16x8 rk1 = *(const bf16x8*)(Kp + (size_t)kr1*2048 + cb0);
    bf16x8 rv0 = *(const bf16x8*)(Vg + (size_t)vrow0*SEQ + vcb);
    bf16x8 rv1 = *(const bf16x8*)(Vg + (size_t)vrow1*SEQ + vcb);
    *(bf16x8*)&Ks[0][kr0*72 + cb0] = rk0;
    *(bf16x8*)&Ks[0][kr1*72 + cb0] = rk1;
    *(bf16x8*)&Vt[0][vrow0*72 + vcb] = rv0;
    *(bf16x8*)&Vt[0][vrow1*72 + vcb] = rv1;
  }
  __syncthreads();
#pragma unroll 1
  for (int kt = 0; kt < 32; ++kt) {
    const int cur = kt & 1;
    bf16x8 rk0, rk1, rv0, rv1;
    if (kt < 31) {
      const short* kb = Kp + (size_t)(kt + 1)*64*2048;
      const short* vb = Vg + (kt + 1)*64;
      rk0 = *(const bf16x8*)(kb + (size_t)kr0*2048 + cb0);
      rk1 = *(const bf16x8*)(kb + (size_t)kr1*2048 + cb0);
      rv0 = *(const bf16x8*)(vb + (size_t)vrow0*SEQ + vcb);
      rv1 = *(const bf16x8*)(vb + (size_t)vrow1*SEQ + vcb);
    }
#pragma unroll
    for (int nt = 0; nt < 4; ++nt) {
      bf16x8 k0 = *(const bf16x8*)&Ks[cur][(nt*16 + row_l)*72 + kg*8];
      bf16x8 k1 = *(const bf16x8*)&Ks[cur][(nt*16 + row_l)*72 + 32 + kg*8];
      f32x4 s = {0.f, 0.f, 0.f, 0.f};
      s = __builtin_amdgcn_mfma_f32_16x16x32_bf16(k0, aq0, s, 0, 0, 0);
      s = __builtin_amdgcn_mfma_f32_16x16x32_bf16(k1, aq1, s, 0, 0, 0);
      f32x4 p;
      p[0] = __expf(s[0]) * inv; p[1] = __expf(s[1]) * inv;
      p[2] = __expf(s[2]) * inv; p[3] = __expf(s[3]) * inv;
      *(f32x4*)&attn_bh[(size_t)(qw + row_l)*SEQ + kt*64 + nt*16 + kg*4] = p;
      bf16x4 pb4;
      pb4[0] = f2b(p[0]); pb4[1] = f2b(p[1]); pb4[2] = f2b(p[2]); pb4[3] = f2b(p[3]);
      *(bf16x4*)&Ps[w][row_l*72 + nt*16 + kg*4] = pb4;
    }
    // in-wave relay: all lanes' Ps writes must land before Ps reads
    asm volatile("s_waitcnt lgkmcnt(0)" ::: "memory");
    __builtin_amdgcn_sched_barrier(0);
#pragma unroll
    for (int half = 0; half < 2; ++half) {
      bf16x8 pb = *(const bf16x8*)&Ps[w][row_l*72 + half*32 + kg*8];
#pragma unroll
      for (int e = 0; e < 4; ++e) {
        bf16x8 va = *(const bf16x8*)&Vt[cur][(e*16 + row_l)*72 + half*32 + kg*8];
        actx[e] = __builtin_amdgcn_mfma_f32_16x16x32_bf16(va, pb, actx[e], 0, 0, 0);
      }
    }
    if (kt < 31) {
      *(bf16x8*)&Ks[cur^1][kr0*72 + cb0] = rk0;
      *(bf16x8*)&Ks[cur^1][kr1*72 + cb0] = rk1;
      *(bf16x8*)&Vt[cur^1][vrow0*72 + vcb] = rv0;
      *(bf16x8*)&Vt[cur^1][vrow1*72 + vcb] = rv1;
    }
    __syncthreads();
  }
  // ctx epilogue: actx[e] = ctx^T: row d = e*16+kg*4+r, col q = row_l
#pragma unroll
  for (int e = 0; e < 4; ++e) {
    bf16x4 o;
    o[0] = f2b(actx[e][0]); o[1] = f2b(actx[e][1]);
    o[2] = f2b(actx[e][2]); o[3] = f2b(actx[e][3]);
    *(bf16x4*)&ctx[(size_t)(b*SEQ + qw + row_l)*DM + h*64 + e*16 + kg*4] = o;
  }
}

// ---------------- launch ----------------

extern "C" void kernel_launch(void* const* d_in, const int* in_sizes, int n_in,
                              void* d_out, int out_size, void* d_ws, size_t ws_size,
                              hipStream_t stream) {
  const float* x    = (const float*)d_in[0];
  const float* Wq   = (const float*)d_in[1];
  const float* bq   = (const float*)d_in[2];
  const float* Wk   = (const float*)d_in[3];
  const float* bk   = (const float*)d_in[4];
  const float* Wv   = (const float*)d_in[5];
  const float* bv   = (const float*)d_in[6];
  const float* Wo   = (const float*)d_in[7];
  const float* bo   = (const float*)d_in[8];
  const float* gate = (const float*)d_in[9];
  const float* ent  = (const float*)d_in[10];

  char* ws = (char*)d_ws;
  short* xb   = (short*)(ws);                          // 4096x1024 bf16 (8 MB); reused as ctx
  short* Wcat = (short*)(ws + ((size_t)8  << 20));     // 3072x1024 bf16 (6 MB)
  short* Wob  = (short*)(ws + ((size_t)14 << 20));     // 1024x1024 bf16 (2 MB)
  float* bcat = (float*)(ws + ((size_t)16 << 20));     // 3072 f32
  short* qkb  = (short*)(ws + ((size_t)17 << 20));     // 4096x2048 bf16 (16 MB)
  short* vtg  = (short*)(ws + ((size_t)33 << 20));     // 32x64x2048 bf16 (16 MB)
  short* ctxb = xb;                                    // reuse (x consumed by gemm1)

  float* outp  = (float*)d_out;
  float* attnp = outp + (size_t)MROWS * DM;

  k_conv<<<2048, 256, 0, stream>>>(x, xb, MROWS*DM);
  k_conv_gate<<<512, 256, 0, stream>>>(Wq, gate, Wcat);
  k_went<<<dim3(1024, 4), 256, 0, stream>>>(Wk, ent, Wcat + (size_t)1024*DM);
  k_conv<<<512, 256, 0, stream>>>(Wv, Wcat + (size_t)2048*DM, 1024*1024);
  k_conv<<<512, 256, 0, stream>>>(Wo, Wob, 1024*1024);
  k_bias<<<12, 256, 0, stream>>>(bq, bk, bv, gate, ent, bcat);

  gemm_bt<1><<<dim3(32, 24), 256, 0, stream>>>(xb, Wcat, bcat, qkb, vtg, MROWS, 3072, DM);
  attn_fused<<<1024, 256, 0, stream>>>(qkb, vtg, attnp, ctxb);
  gemm_bt<0><<<dim3(32, 8), 256, 0, stream>>>(ctxb, Wob, bo, outp, nullptr, MROWS, DM, DM);
}

// Round 5
// 281.316 us; speedup vs baseline: 1.4066x; 1.1912x over previous
//
#include <hip/hip_runtime.h>
#include <hip/hip_bf16.h>

#define DM 1024
#define NH 16
#define HD 64
#define BATCH 2
#define SEQ 2048
#define MROWS (BATCH*SEQ)   // 4096

typedef __attribute__((ext_vector_type(8))) short bf16x8;
typedef __attribute__((ext_vector_type(4))) short bf16x4;
typedef __attribute__((ext_vector_type(4))) float f32x4;
typedef __attribute__((ext_vector_type(4))) unsigned u32x4;

__device__ __forceinline__ short f2b(float f) {
  union { float f; unsigned u; } x; x.f = f;
  unsigned r = x.u + 0x7fffu + ((x.u >> 16) & 1u);
  return (short)(r >> 16);
}

__device__ __forceinline__ unsigned cvtpk(float lo, float hi) {
  unsigned r;
  asm("v_cvt_pk_bf16_f32 %0, %1, %2" : "=v"(r) : "v"(lo), "v"(hi));
  return r;
}

__device__ __forceinline__ void gload16(const void* g, void* l) {
  __builtin_amdgcn_global_load_lds((const __attribute__((address_space(1))) unsigned int*)g,
                                   (__attribute__((address_space(3))) unsigned int*)l, 16, 0, 0);
}

// ---------------- prep kernels ----------------

__global__ void k_conv(const float* __restrict__ src, short* __restrict__ dst, int n) {
  int i = (blockIdx.x * 256 + threadIdx.x) * 8;
  if (i >= n) return;
  const float4* s4 = (const float4*)(src + i);
  float4 a = s4[0], b = s4[1];
  bf16x8 o;
  o[0]=f2b(a.x); o[1]=f2b(a.y); o[2]=f2b(a.z); o[3]=f2b(a.w);
  o[4]=f2b(b.x); o[5]=f2b(b.y); o[6]=f2b(b.z); o[7]=f2b(b.w);
  *(bf16x8*)(dst + i) = o;
}

// Wq rows scaled by sigmoid(gate[row]) * 0.125 (fold in 1/sqrt(HD))
__global__ void k_conv_gate(const float* __restrict__ Wq, const float* __restrict__ gate,
                            short* __restrict__ dst) {
  int i = (blockIdx.x * 256 + threadIdx.x) * 8;
  int row = i >> 10;
  float sg = 0.125f / (1.f + __expf(-gate[row]));
  const float4* s4 = (const float4*)(Wq + i);
  float4 a = s4[0], b = s4[1];
  bf16x8 o;
  o[0]=f2b(a.x*sg); o[1]=f2b(a.y*sg); o[2]=f2b(a.z*sg); o[3]=f2b(a.w*sg);
  o[4]=f2b(b.x*sg); o[5]=f2b(b.y*sg); o[6]=f2b(b.z*sg); o[7]=f2b(b.w*sg);
  *(bf16x8*)(dst + i) = o;
}

// Wk_ent[h*64+e][c] = sum_d ent[h][d][e] * Wk[h*64+d][c]
__global__ void k_went(const float* __restrict__ Wk, const float* __restrict__ ent,
                       short* __restrict__ dst) {
  int r = blockIdx.x;            // 0..1023
  int h = r >> 6, e = r & 63;
  int c = blockIdx.y * 256 + threadIdx.x;
  float acc = 0.f;
#pragma unroll 8
  for (int d = 0; d < 64; ++d)
    acc += ent[h*4096 + d*64 + e] * Wk[(size_t)(h*64 + d)*DM + c];
  dst[(size_t)r*DM + c] = f2b(acc);
}

__global__ void k_bias(const float* __restrict__ bq, const float* __restrict__ bk,
                       const float* __restrict__ bv, const float* __restrict__ gate,
                       const float* __restrict__ ent, float* __restrict__ bcat) {
  int i = blockIdx.x * 256 + threadIdx.x;  // < 3072
  float v;
  if (i < 1024) {
    v = bq[i] * (0.125f / (1.f + __expf(-gate[i])));
  } else if (i < 2048) {
    int rr = i - 1024, h = rr >> 6, e = rr & 63;
    float a = 0.f;
    for (int d = 0; d < 64; ++d) a += bk[h*64 + d] * ent[h*4096 + d*64 + e];
    v = a;
  } else {
    v = bv[i - 2048];
  }
  bcat[i] = v;
}

// ---------------- GEMM: C[m,n] = sum_k A[m,k]*B[n,k] + bias[n] ----------------
// MODE 0: fp32 C row-major (stride N). MODE 1: cols<2048 -> bf16 QK buffer
// (stride 2048); cols>=2048 -> V written TRANSPOSED into vt[bh][d][s].

template<int MODE>
__global__ __launch_bounds__(256) void gemm_bt(const short* __restrict__ A,
                                               const short* __restrict__ B,
                                               const float* __restrict__ bias,
                                               void* __restrict__ C,
                                               short* __restrict__ vt,
                                               int M, int N, int K) {
  __shared__ __align__(16) short As[128*64];
  __shared__ __align__(16) short Bs[128*64];
  const int t = threadIdx.x, l = t & 63, w = t >> 6;
  const int wr = w >> 1, wc = w & 1;
  const int bm = blockIdx.x, bn = blockIdx.y;
  const int row_l = l & 15, kg = l >> 4;
  f32x4 acc[4][4];
  {
    f32x4 z = {0.f, 0.f, 0.f, 0.f};
#pragma unroll
    for (int m = 0; m < 4; ++m)
#pragma unroll
      for (int n = 0; n < 4; ++n) acc[m][n] = z;
  }
  for (int k0 = 0; k0 < K; k0 += 64) {
#pragma unroll
    for (int i = 0; i < 4; ++i) {
      int idx = i * 256 + t;
      int row = idx >> 3, cb = (idx & 7) * 8;
      gload16(A + (size_t)(bm*128 + row)*K + k0 + cb, &As[idx*8]);
      gload16(B + (size_t)(bn*128 + row)*K + k0 + cb, &Bs[idx*8]);
    }
    __syncthreads();
#pragma unroll
    for (int ks = 0; ks < 2; ++ks) {
      bf16x8 af[4], bfv[4];
#pragma unroll
      for (int m = 0; m < 4; ++m)
        af[m] = *(const bf16x8*)&As[(wr*64 + m*16 + row_l)*64 + ks*32 + kg*8];
#pragma unroll
      for (int n = 0; n < 4; ++n)
        bfv[n] = *(const bf16x8*)&Bs[(wc*64 + n*16 + row_l)*64 + ks*32 + kg*8];
#pragma unroll
      for (int m = 0; m < 4; ++m)
#pragma unroll
        for (int n = 0; n < 4; ++n)
          acc[m][n] = __builtin_amdgcn_mfma_f32_16x16x32_bf16(af[m], bfv[n], acc[m][n], 0, 0, 0);
    }
    __syncthreads();
  }
  const int r0 = bm*128 + wr*64, c0 = bn*128 + wc*64;
  if (MODE == 1 && c0 >= 2048) {
    // V region: write transposed vt[(b*16+h)*64 + d][s]
    const int bb = (bm*128) >> 11;
#pragma unroll
    for (int n = 0; n < 4; ++n) {
      int cv = c0 + n*16 + row_l - 2048;
      int hh = cv >> 6, dd = cv & 63;
      float bvs = bias[c0 + n*16 + row_l];
      short* vrow = vt + ((size_t)((bb*16 + hh)*64 + dd))*SEQ;
#pragma unroll
      for (int m = 0; m < 4; ++m) {
        int s0 = (r0 + m*16 + kg*4) & (SEQ-1);
        bf16x4 o;
        o[0]=f2b(acc[m][n][0]+bvs); o[1]=f2b(acc[m][n][1]+bvs);
        o[2]=f2b(acc[m][n][2]+bvs); o[3]=f2b(acc[m][n][3]+bvs);
        *(bf16x4*)&vrow[s0] = o;
      }
    }
  } else {
#pragma unroll
    for (int n = 0; n < 4; ++n) {
      int col = c0 + n*16 + row_l;
      float bvs = bias[col];
#pragma unroll
      for (int m = 0; m < 4; ++m) {
#pragma unroll
        for (int r = 0; r < 4; ++r) {
          int row = r0 + m*16 + kg*4 + r;
          float v = acc[m][n][r] + bvs;
          if (MODE == 1) ((short*)C)[(size_t)row*2048 + col] = f2b(v);
          else           ((float*)C)[(size_t)row*N + col] = v;
        }
      }
    }
  }
}

// ---------------- fused attention ----------------
// qk: (4096 x 2048) bf16: Q at col h*64, K' at 1024+h*64 (Q pre-scaled by 1/8).
// vtg: [bh][d][s] bf16 (pre-transposed V).
// K staged with bit-permuted rows g(a) so the QK^T S^T fragments are already
// PV-B-operand-aligned: P stays in registers (cvt_pk only, no LDS relay).
// LDS tiles [64][64] shorts, XOR slot swizzle; K+V double-buffered, 1 barrier/tile.

__global__ __launch_bounds__(256) void attn_fused(const short* __restrict__ qk,
                                                  const short* __restrict__ vtg,
                                                  float* __restrict__ attn_out,
                                                  short* __restrict__ ctx) {
  __shared__ __align__(16) short Ks[2][64*64];
  __shared__ __align__(16) short Vt[2][64*64];
  const int t = threadIdx.x, l = t & 63, w = t >> 6;
  const int row_l = l & 15, kg = l >> 4;
  const int rsl = row_l & 7;
  const int blk = blockIdx.x;
  const int bh = blk >> 5, q0 = (blk & 31) * 64;
  const int b = bh >> 4, h = bh & 15;
  const short* Qp = qk + (size_t)b*SEQ*2048 + h*64;
  const short* Kp = qk + (size_t)b*SEQ*2048 + 1024 + h*64;
  const short* Vg = vtg + (size_t)bh*64*SEQ;
  float* attn_bh = attn_out + (size_t)bh*SEQ*SEQ;
  const int qw = q0 + w*16;

  const bf16x8 aq0 = *(const bf16x8*)(Qp + (size_t)(qw + row_l)*2048 + kg*8);
  const bf16x8 aq1 = *(const bf16x8*)(Qp + (size_t)(qw + row_l)*2048 + 32 + kg*8);

  // staging: LDS row a holds K key g(a); V rows natural (d)
  const int a0 = t >> 3, a1 = a0 + 32;
  const int c8 = (t & 7) * 8;
  const int g0 = (a0 & 0x23) | ((a0 & 0x0C) << 1) | ((a0 & 0x10) >> 2);
  const int g1 = (a1 & 0x23) | ((a1 & 0x0C) << 1) | ((a1 & 0x10) >> 2);
  const int wof0 = a0*64 + (c8 ^ ((a0 & 7) << 3));   // a1&7 == a0&7
  const int wof1 = a1*64 + (c8 ^ ((a0 & 7) << 3));

  // ---- pass 1: rsum; K double-buffered, 1 barrier/tile ----
  float rsum = 0.f;
  {
    bf16x8 rk0 = *(const bf16x8*)(Kp + (size_t)g0*2048 + c8);
    bf16x8 rk1 = *(const bf16x8*)(Kp + (size_t)g1*2048 + c8);
    *(bf16x8*)&Ks[0][wof0] = rk0;
    *(bf16x8*)&Ks[0][wof1] = rk1;
  }
  __syncthreads();
#pragma unroll 1
  for (int kt = 0; kt < 32; ++kt) {
    const int cur = kt & 1;
    bf16x8 rk0, rk1;
    if (kt < 31) {
      const short* kb = Kp + (size_t)(kt + 1)*64*2048;
      rk0 = *(const bf16x8*)(kb + (size_t)g0*2048 + c8);
      rk1 = *(const bf16x8*)(kb + (size_t)g1*2048 + c8);
    }
    __builtin_amdgcn_s_setprio(1);
#pragma unroll
    for (int nt = 0; nt < 4; ++nt) {
      const int row = nt*16 + row_l;
      bf16x8 k0 = *(const bf16x8*)&Ks[cur][row*64 + ((kg ^ rsl) << 3)];
      bf16x8 k1 = *(const bf16x8*)&Ks[cur][row*64 + (((kg|4) ^ rsl) << 3)];
      f32x4 s = {0.f, 0.f, 0.f, 0.f};
      s = __builtin_amdgcn_mfma_f32_16x16x32_bf16(k0, aq0, s, 0, 0, 0);
      s = __builtin_amdgcn_mfma_f32_16x16x32_bf16(k1, aq1, s, 0, 0, 0);
      rsum += (__expf(s[0]) + __expf(s[1])) + (__expf(s[2]) + __expf(s[3]));
    }
    __builtin_amdgcn_s_setprio(0);
    if (kt < 31) {
      *(bf16x8*)&Ks[cur^1][wof0] = rk0;
      *(bf16x8*)&Ks[cur^1][wof1] = rk1;
    }
    __syncthreads();
  }
  rsum += __shfl_xor(rsum, 16);
  rsum += __shfl_xor(rsum, 32);
  const float inv = 1.f / rsum;

  f32x4 actx[4];
  {
    f32x4 z = {0.f, 0.f, 0.f, 0.f};
#pragma unroll
    for (int e = 0; e < 4; ++e) actx[e] = z;
  }

  // ---- pass 2: recompute, write attn, PV (P in-register); 1 barrier/tile ----
  {
    bf16x8 rk0 = *(const bf16x8*)(Kp + (size_t)g0*2048 + c8);
    bf16x8 rk1 = *(const bf16x8*)(Kp + (size_t)g1*2048 + c8);
    bf16x8 rv0 = *(const bf16x8*)(Vg + (size_t)a0*SEQ + c8);
    bf16x8 rv1 = *(const bf16x8*)(Vg + (size_t)a1*SEQ + c8);
    *(bf16x8*)&Ks[0][wof0] = rk0;
    *(bf16x8*)&Ks[0][wof1] = rk1;
    *(bf16x8*)&Vt[0][wof0] = rv0;
    *(bf16x8*)&Vt[0][wof1] = rv1;
  }
  __syncthreads();
#pragma unroll 1
  for (int kt = 0; kt < 32; ++kt) {
    const int cur = kt & 1;
    bf16x8 rk0, rk1, rv0, rv1;
    if (kt < 31) {
      const short* kb = Kp + (size_t)(kt + 1)*64*2048;
      const short* vb = Vg + (kt + 1)*64;
      rk0 = *(const bf16x8*)(kb + (size_t)g0*2048 + c8);
      rk1 = *(const bf16x8*)(kb + (size_t)g1*2048 + c8);
      rv0 = *(const bf16x8*)(vb + (size_t)a0*SEQ + c8);
      rv1 = *(const bf16x8*)(vb + (size_t)a1*SEQ + c8);
    }
    f32x4 pf[4];
    __builtin_amdgcn_s_setprio(1);
#pragma unroll
    for (int nt = 0; nt < 4; ++nt) {
      const int row = nt*16 + row_l;
      bf16x8 k0 = *(const bf16x8*)&Ks[cur][row*64 + ((kg ^ rsl) << 3)];
      bf16x8 k1 = *(const bf16x8*)&Ks[cur][row*64 + (((kg|4) ^ rsl) << 3)];
      f32x4 s = {0.f, 0.f, 0.f, 0.f};
      s = __builtin_amdgcn_mfma_f32_16x16x32_bf16(k0, aq0, s, 0, 0, 0);
      s = __builtin_amdgcn_mfma_f32_16x16x32_bf16(k1, aq1, s, 0, 0, 0);
      f32x4 p;
      p[0] = __expf(s[0]) * inv; p[1] = __expf(s[1]) * inv;
      p[2] = __expf(s[2]) * inv; p[3] = __expf(s[3]) * inv;
      // key for (nt,kg,r) = kt*64 + g(nt*16+kg*4+r) = kt*64 + (nt>>1)*32 + kg*8 + (nt&1)*4 + r
      *(f32x4*)&attn_bh[(size_t)(qw + row_l)*SEQ + kt*64 + (nt&2)*16 + kg*8 + (nt&1)*4] = p;
      pf[nt] = p;
    }
    // PV: pb for half h = keys h*32 + kg*8 + 0..7 = pf[2h](0..3) ++ pf[2h+1](0..3)
#pragma unroll
    for (int hh = 0; hh < 2; ++hh) {
      u32x4 pq;
      pq[0] = cvtpk(pf[2*hh][0],   pf[2*hh][1]);
      pq[1] = cvtpk(pf[2*hh][2],   pf[2*hh][3]);
      pq[2] = cvtpk(pf[2*hh+1][0], pf[2*hh+1][1]);
      pq[3] = cvtpk(pf[2*hh+1][2], pf[2*hh+1][3]);
      bf16x8 pb = *(bf16x8*)&pq;
      const int vslot = ((kg | (hh << 2)) ^ rsl) << 3;
#pragma unroll
      for (int e = 0; e < 4; ++e) {
        bf16x8 va = *(const bf16x8*)&Vt[cur][(e*16 + row_l)*64 + vslot];
        actx[e] = __builtin_amdgcn_mfma_f32_16x16x32_bf16(va, pb, actx[e], 0, 0, 0);
      }
    }
    __builtin_amdgcn_s_setprio(0);
    if (kt < 31) {
      *(bf16x8*)&Ks[cur^1][wof0] = rk0;
      *(bf16x8*)&Ks[cur^1][wof1] = rk1;
      *(bf16x8*)&Vt[cur^1][wof0] = rv0;
      *(bf16x8*)&Vt[cur^1][wof1] = rv1;
    }
    __syncthreads();
  }
  // ctx epilogue: actx[e] = ctx^T: row d = e*16+kg*4+r, col q = row_l
#pragma unroll
  for (int e = 0; e < 4; ++e) {
    int2 o;
    o.x = (int)cvtpk(actx[e][0], actx[e][1]);
    o.y = (int)cvtpk(actx[e][2], actx[e][3]);
    *(int2*)&ctx[(size_t)(b*SEQ + qw + row_l)*DM + h*64 + e*16 + kg*4] = o;
  }
}

// ---------------- launch ----------------

extern "C" void kernel_launch(void* const* d_in, const int* in_sizes, int n_in,
                              void* d_out, int out_size, void* d_ws, size_t ws_size,
                              hipStream_t stream) {
  const float* x    = (const float*)d_in[0];
  const float* Wq   = (const float*)d_in[1];
  const float* bq   = (const float*)d_in[2];
  const float* Wk   = (const float*)d_in[3];
  const float* bk   = (const float*)d_in[4];
  const float* Wv   = (const float*)d_in[5];
  const float* bv   = (const float*)d_in[6];
  const float* Wo   = (const float*)d_in[7];
  const float* bo   = (const float*)d_in[8];
  const float* gate = (const float*)d_in[9];
  const float* ent  = (const float*)d_in[10];

  char* ws = (char*)d_ws;
  short* xb   = (short*)(ws);                          // 4096x1024 bf16 (8 MB); reused as ctx
  short* Wcat = (short*)(ws + ((size_t)8  << 20));     // 3072x1024 bf16 (6 MB)
  short* Wob  = (short*)(ws + ((size_t)14 << 20));     // 1024x1024 bf16 (2 MB)
  float* bcat = (float*)(ws + ((size_t)16 << 20));     // 3072 f32
  short* qkb  = (short*)(ws + ((size_t)17 << 20));     // 4096x2048 bf16 (16 MB)
  short* vtg  = (short*)(ws + ((size_t)33 << 20));     // 32x64x2048 bf16 (16 MB)
  short* ctxb = xb;                                    // reuse (x consumed by gemm1)

  float* outp  = (float*)d_out;
  float* attnp = outp + (size_t)MROWS * DM;

  k_conv<<<2048, 256, 0, stream>>>(x, xb, MROWS*DM);
  k_conv_gate<<<512, 256, 0, stream>>>(Wq, gate, Wcat);
  k_went<<<dim3(1024, 4), 256, 0, stream>>>(Wk, ent, Wcat + (size_t)1024*DM);
  k_conv<<<512, 256, 0, stream>>>(Wv, Wcat + (size_t)2048*DM, 1024*1024);
  k_conv<<<512, 256, 0, stream>>>(Wo, Wob, 1024*1024);
  k_bias<<<12, 256, 0, stream>>>(bq, bk, bv, gate, ent, bcat);

  gemm_bt<1><<<dim3(32, 24), 256, 0, stream>>>(xb, Wcat, bcat, qkb, vtg, MROWS, 3072, DM);
  attn_fused<<<1024, 256, 0, stream>>>(qkb, vtg, attnp, ctxb);
  gemm_bt<0><<<dim3(32, 8), 256, 0, stream>>>(ctxb, Wob, bo, outp, nullptr, MROWS, DM, DM);
}